// Round 6
// baseline (102.663 us; speedup 1.0000x reference)
//
#include <hip/hip_runtime.h>

typedef unsigned short u16;
typedef unsigned int   u32;
typedef u16   u16x4 __attribute__((ext_vector_type(4)));
typedef u16   u16x8 __attribute__((ext_vector_type(8)));
typedef short s16x8 __attribute__((ext_vector_type(8)));
typedef float f32x4 __attribute__((ext_vector_type(4)));

#define S_TOK 4096
#define MDIM  2048
#define NDIM  2048
#define HDIM  1024
#define TDIM  512

__device__ __forceinline__ u16 f2bf(float f) {
  u32 u = __float_as_uint(f);
  u = u + 0x7fffu + ((u >> 16) & 1u);   // round-to-nearest-even
  return (u16)(u >> 16);
}

__device__ __forceinline__ void gl2lds16(const void* g, void* l) {
  __builtin_amdgcn_global_load_lds(
      (const __attribute__((address_space(1))) void*)g,
      (__attribute__((address_space(3))) void*)l, 16, 0, 0);
}

// ---- merged prep: w1 transpose->bf16, w2/b2 row-sums, ssum zero, gate+x->bf16 ----
__global__ __launch_bounds__(256) void prep_all(const float* __restrict__ w1,
                                                u16* __restrict__ w1t,
                                                const float* __restrict__ w2,
                                                const float* __restrict__ b2,
                                                float* __restrict__ w2sum,
                                                float* __restrict__ b2sum,
                                                const float* __restrict__ x,
                                                const float* __restrict__ wg,
                                                float* __restrict__ g,
                                                u16* __restrict__ xbf,
                                                float* __restrict__ ssum) {
  __shared__ float tile[32][33];
  int b = blockIdx.x;
  int t = threadIdx.x;
  if (b < 4096) {
    // ---- w1 [E][M][H] fp32 -> w1t [E*H][M] bf16 ----
    int e   = b >> 11;
    int idx = b & 2047;
    int m0  = (idx >> 5) << 5;
    int h0  = (idx & 31) << 5;
    int r = t >> 3, q = t & 7;
    const float* src = w1 + ((size_t)e * MDIM + (m0 + r)) * HDIM + h0 + q * 4;
    f32x4 v = *(const f32x4*)src;
    tile[r][q*4+0] = v[0]; tile[r][q*4+1] = v[1];
    tile[r][q*4+2] = v[2]; tile[r][q*4+3] = v[3];
    __syncthreads();
    u16x4 o;
    o[0] = f2bf(tile[q*4+0][r]);
    o[1] = f2bf(tile[q*4+1][r]);
    o[2] = f2bf(tile[q*4+2][r]);
    o[3] = f2bf(tile[q*4+3][r]);
    u16* dst = w1t + ((size_t)e * HDIM + (h0 + r)) * MDIM + m0 + q * 4;
    *(u16x4*)dst = o;
  } else if (b < 4609) {
    // ---- w2sum / b2sum ----
    int bid  = b - 4096;
    int row  = bid * 4 + (t >> 6);
    int lane = t & 63;
    const float* src;
    if (row < NDIM)          src = w2 + (size_t)row * MDIM;
    else if (row < NDIM + 2) src = b2 + (size_t)(row - NDIM) * MDIM;
    else return;
    float acc = 0.f;
    for (int m = lane * 4; m < MDIM; m += 256) {
      f32x4 v = *(const f32x4*)(src + m);
      acc += v[0] + v[1] + v[2] + v[3];
    }
    #pragma unroll
    for (int off = 32; off; off >>= 1) acc += __shfl_xor(acc, off);
    if (lane == 0) {
      if (row < NDIM) w2sum[row] = acc;
      else            b2sum[row - NDIM] = acc;
    }
  } else if (b == 4609) {
    // ---- zero ssum ----
    f32x4 z = {0.f, 0.f, 0.f, 0.f};
    #pragma unroll
    for (int i = 0; i < 8; ++i)
      *(f32x4*)(ssum + (t + i * 256) * 4) = z;
  } else {
    // ---- fp32 gate + x->bf16 ----
    int bid  = b - 4610;
    int s    = bid * 4 + (t >> 6);
    int lane = t & 63;
    const float* xr = x + (size_t)s * MDIM;
    u16* xbr = xbf + (size_t)s * MDIM;
    float l0 = 0.f, l1 = 0.f;
    for (int m = lane * 4; m < MDIM; m += 256) {
      f32x4 xv = *(const f32x4*)(xr + m);
      f32x4 wa = *(const f32x4*)(wg + 2 * m);
      f32x4 wb = *(const f32x4*)(wg + 2 * m + 4);
      l0 += xv[0]*wa[0] + xv[1]*wa[2] + xv[2]*wb[0] + xv[3]*wb[2];
      l1 += xv[0]*wa[1] + xv[1]*wa[3] + xv[2]*wb[1] + xv[3]*wb[3];
      u16x4 o; o[0]=f2bf(xv[0]); o[1]=f2bf(xv[1]); o[2]=f2bf(xv[2]); o[3]=f2bf(xv[3]);
      *(u16x4*)(xbr + m) = o;
    }
    #pragma unroll
    for (int off = 32; off; off >>= 1) {
      l0 += __shfl_xor(l0, off);
      l1 += __shfl_xor(l1, off);
    }
    if (lane == 0) {
      float mx = fmaxf(l0, l1);
      float e0 = expf(l0 - mx), e1 = expf(l1 - mx);
      float inv = 1.f / (e0 + e1);
      g[2*s]   = e0 * inv;
      g[2*s+1] = e1 * inv;
    }
  }
}

// ---- main GEMM: 256x128 tile, 64x64 wave tiles, A LDS-staged, B global->regs ----
#define BM 256
#define BN 128
#define BK 64
#define KT (MDIM / BK)   // 32

#define MFMA_BF16 __builtin_amdgcn_mfma_f32_16x16x32_bf16

__global__ __launch_bounds__(512, 2) void gemm_fused(const u16* __restrict__ xbf,
                                                     const u16* __restrict__ w1t,
                                                     const float* __restrict__ b1,
                                                     const float* __restrict__ w2sum,
                                                     float* __restrict__ ssum) {
  __shared__ u16 As[2][BM * BK];   // 2 x 32 KB

  int bid  = blockIdx.x;
  int tile = (bid & 7) * 32 + (bid >> 3);   // 256 % 8 == 0: bijective XCD swizzle
  int bm = tile >> 4;     // 0..15
  int bn = tile & 15;     // 0..15
  int gs0 = bm * BM;
  int gn0 = bn * BN;

  int tid  = threadIdx.x;
  int lane = tid & 63;
  int wid  = tid >> 6;               // 0..7
  int wr = wid >> 1, wc = wid & 1;   // 4(M) x 2(N); wave tile 64x64
  int fr = lane & 15, fg = lane >> 4;

  // A staging: wave stages 32 rows (4 issues of 8); chunk-swizzled source (rule #21)
  int lr = lane >> 3;
  int lc = (lane & 7) ^ lr;
  const u16* aS = xbf + (size_t)(gs0 + wid * 32 + lr) * MDIM + lc * 8;
  int aD = (wid * 32) * BK;          // wave-uniform LDS u16 offset

  // A frag-read offsets (u16 units), kk=0; kk=1 is ^32
  int ch0 = (fg ^ (fr & 7)) * 8;
  int aOff[4];
  #pragma unroll
  for (int i = 0; i < 4; ++i) aOff[i] = (wr * 64 + i * 16 + fr) * BK + ch0;

  // B direct-from-global base: frag(j,kk,k0) at bBase + j*16*MDIM + kk*32 + k0
  const u16* bBase = w1t + (size_t)(gn0 + wc * 64 + fr) * MDIM + fg * 8;

  f32x4 acc[4][4] = {};
  s16x8 bA[8], bB[8];   // B-frag register double buffer [kk*4+j]

  // ---- prologue: A(0)->buf0, B(0)->bA, A(1)->buf1 ----
  #pragma unroll
  for (int q = 0; q < 4; ++q)
    gl2lds16(aS + q * 8 * MDIM, &As[0][aD + q * 8 * BK]);
  #pragma unroll
  for (int kk = 0; kk < 2; ++kk)
    #pragma unroll
    for (int j = 0; j < 4; ++j)
      bA[kk * 4 + j] = *(const s16x8*)(bBase + (size_t)j * 16 * MDIM + kk * 32);
  #pragma unroll
  for (int q = 0; q < 4; ++q)
    gl2lds16(aS + BK + q * 8 * MDIM, &As[1][aD + q * 8 * BK]);
  asm volatile("s_waitcnt vmcnt(4)" ::: "memory");   // A(0)+B(0) landed; A(1) in flight
  __builtin_amdgcn_s_barrier();

  // ---- main loop, unrolled x2 for static B-reg double buffer ----
  #pragma unroll 1
  for (int tt = 0; tt < KT / 2; ++tt) {
    // ===== even t = 2*tt: compute from As[0]+bA, prefetch B(t+1)->bB =====
    {
      int t = 2 * tt;
      int nk = (t + 1) * BK;
      #pragma unroll
      for (int kk = 0; kk < 2; ++kk)
        #pragma unroll
        for (int j = 0; j < 4; ++j)
          bB[kk * 4 + j] = *(const s16x8*)(bBase + (size_t)j * 16 * MDIM + kk * 32 + nk);
      #pragma unroll
      for (int kk = 0; kk < 2; ++kk) {
        int x32 = kk * 32;
        s16x8 af[4];
        #pragma unroll
        for (int i = 0; i < 4; ++i) af[i] = *(const s16x8*)(&As[0][aOff[i] ^ x32]);
        __builtin_amdgcn_s_setprio(1);
        #pragma unroll
        for (int i = 0; i < 4; ++i)
          #pragma unroll
          for (int j = 0; j < 4; ++j)
            acc[i][j] = MFMA_BF16(af[i], bA[kk * 4 + j], acc[i][j], 0, 0, 0);
        __builtin_amdgcn_s_setprio(0);
      }
      asm volatile("s_waitcnt vmcnt(8)" ::: "memory");  // A(t+1) landed; B(t+1) may fly
      __builtin_amdgcn_s_barrier();                     // all reads of As[0] done
      if (t + 2 < KT) {
        int nk2 = (t + 2) * BK;
        #pragma unroll
        for (int q = 0; q < 4; ++q)
          gl2lds16(aS + nk2 + q * 8 * MDIM, &As[0][aD + q * 8 * BK]);
      }
      asm volatile("s_waitcnt vmcnt(4)" ::: "memory");  // drain B(t+1) mostly
    }
    // ===== odd t = 2*tt+1: compute from As[1]+bB, prefetch B(t+1)->bA =====
    {
      int t = 2 * tt + 1;
      bool notlast = (t + 1 < KT);
      int nk = (t + 1) * BK;
      if (notlast) {
        #pragma unroll
        for (int kk = 0; kk < 2; ++kk)
          #pragma unroll
          for (int j = 0; j < 4; ++j)
            bA[kk * 4 + j] = *(const s16x8*)(bBase + (size_t)j * 16 * MDIM + kk * 32 + nk);
      }
      #pragma unroll
      for (int kk = 0; kk < 2; ++kk) {
        int x32 = kk * 32;
        s16x8 af[4];
        #pragma unroll
        for (int i = 0; i < 4; ++i) af[i] = *(const s16x8*)(&As[1][aOff[i] ^ x32]);
        __builtin_amdgcn_s_setprio(1);
        #pragma unroll
        for (int i = 0; i < 4; ++i)
          #pragma unroll
          for (int j = 0; j < 4; ++j)
            acc[i][j] = MFMA_BF16(af[i], bB[kk * 4 + j], acc[i][j], 0, 0, 0);
        __builtin_amdgcn_s_setprio(0);
      }
      if (notlast) {
        asm volatile("s_waitcnt vmcnt(8)" ::: "memory");
        __builtin_amdgcn_s_barrier();
        if (t + 2 < KT) {
          int nk2 = (t + 2) * BK;
          #pragma unroll
          for (int q = 0; q < 4; ++q)
            gl2lds16(aS + nk2 + q * 8 * MDIM, &As[1][aD + q * 8 * BK]);
        }
        asm volatile("s_waitcnt vmcnt(4)" ::: "memory");
      }
    }
  }

  // epilogue: relu(acc + b1) * w2sum, reduce 64 cols -> atomicAdd ssum[e][s]
  int e = gn0 >> 10;   // BN=128 divides 1024: block within one expert
  float b1v[4], w2v[4];
  #pragma unroll
  for (int j = 0; j < 4; ++j) {
    int n = gn0 + wc * 64 + j * 16 + fr;
    b1v[j] = b1[n];
    w2v[j] = w2sum[n];
  }
  #pragma unroll
  for (int i = 0; i < 4; ++i) {
    #pragma unroll
    for (int r = 0; r < 4; ++r) {
      float sv = 0.f;
      #pragma unroll
      for (int j = 0; j < 4; ++j)
        sv += fmaxf(acc[i][j][r] + b1v[j], 0.f) * w2v[j];
      sv += __shfl_xor(sv, 1);
      sv += __shfl_xor(sv, 2);
      sv += __shfl_xor(sv, 4);
      sv += __shfl_xor(sv, 8);
      if (fr == 0) {
        int s = gs0 + wr * 64 + i * 16 + fg * 4 + r;
        atomicAdd(&ssum[(size_t)e * S_TOK + s], sv);
      }
    }
  }
}

// ---- summed = g0*(ssum0+b2sum0)+g1*(ssum1+b2sum1); log_softmax over T ----
__global__ __launch_bounds__(512) void finalize(const float* __restrict__ g,
                                                const float* __restrict__ ssum,
                                                const float* __restrict__ b2sum,
                                                float* __restrict__ out) {
  __shared__ float sA[8];
  __shared__ float sB[2];
  int b = blockIdx.x;
  int t = threadIdx.x;
  int s = b * TDIM + t;
  int lane = t & 63, wid = t >> 6;
  float g0 = g[2*s], g1 = g[2*s+1];
  float v = g0 * (ssum[s] + b2sum[0]) + g1 * (ssum[S_TOK + s] + b2sum[1]);
  float m = v;
  #pragma unroll
  for (int off = 32; off; off >>= 1) m = fmaxf(m, __shfl_xor(m, off));
  if (lane == 0) sA[wid] = m;
  __syncthreads();
  if (t == 0) {
    float mm = sA[0];
    #pragma unroll
    for (int i = 1; i < 8; ++i) mm = fmaxf(mm, sA[i]);
    sB[0] = mm;
  }
  __syncthreads();
  float gm = sB[0];
  float ex = expf(v - gm);
  float sum = ex;
  #pragma unroll
  for (int off = 32; off; off >>= 1) sum += __shfl_xor(sum, off);
  if (lane == 0) sA[wid] = sum;
  __syncthreads();
  if (t == 0) {
    float ss = 0.f;
    #pragma unroll
    for (int i = 0; i < 8; ++i) ss += sA[i];
    sB[1] = logf(ss);
  }
  __syncthreads();
  out[s] = v - gm - sB[1];
}

extern "C" void kernel_launch(void* const* d_in, const int* in_sizes, int n_in,
                              void* d_out, int out_size, void* d_ws, size_t ws_size,
                              hipStream_t stream) {
  const float* x  = (const float*)d_in[0];
  const float* wg = (const float*)d_in[1];
  const float* w1 = (const float*)d_in[2];
  const float* b1 = (const float*)d_in[3];
  const float* w2 = (const float*)d_in[4];
  const float* b2 = (const float*)d_in[5];
  float* out = (float*)d_out;

  char* ws = (char*)d_ws;
  u16*   w1t   = (u16*)ws;                     // 8,388,608 B
  u16*   xbf   = (u16*)(ws + 8388608);         // 16,777,216 B
  float* ssum  = (float*)(ws + 25165824);      // 32,768 B
  float* gbuf  = (float*)(ws + 25198592);      // 32,768 B
  float* w2sum = (float*)(ws + 25231360);      // 8,192 B
  float* b2sum = (float*)(ws + 25239552);      // 8 B

  hipLaunchKernelGGL(prep_all,   dim3(5634), dim3(256), 0, stream,
                     w1, w1t, w2, b2, w2sum, b2sum, x, wg, gbuf, xbf, ssum);
  hipLaunchKernelGGL(gemm_fused, dim3(256),  dim3(512), 0, stream, xbf, w1t, b1, w2sum, ssum);
  hipLaunchKernelGGL(finalize,   dim3(8),    dim3(512), 0, stream, gbuf, ssum, b2sum, out);
}

// Round 7
// 62.002 us; speedup vs baseline: 1.6558x; 1.6558x over previous
//
#include <hip/hip_runtime.h>

typedef unsigned short u16;
typedef unsigned int   u32;
typedef u16   u16x4 __attribute__((ext_vector_type(4)));
typedef u16   u16x8 __attribute__((ext_vector_type(8)));
typedef short s16x8 __attribute__((ext_vector_type(8)));
typedef float f32x4 __attribute__((ext_vector_type(4)));

#define S_TOK 4096
#define MDIM  2048
#define NDIM  2048
#define HDIM  1024
#define TDIM  512

__device__ __forceinline__ u16 f2bf(float f) {
  u32 u = __float_as_uint(f);
  u = u + 0x7fffu + ((u >> 16) & 1u);   // round-to-nearest-even
  return (u16)(u >> 16);
}

__device__ __forceinline__ void gl2lds16(const void* g, void* l) {
  __builtin_amdgcn_global_load_lds(
      (const __attribute__((address_space(1))) void*)g,
      (__attribute__((address_space(3))) void*)l, 16, 0, 0);
}

// ---- merged prep: w1 transpose->bf16, w2/b2 row-sums, ssum zero, gate+x->bf16 ----
__global__ __launch_bounds__(256) void prep_all(const float* __restrict__ w1,
                                                u16* __restrict__ w1t,
                                                const float* __restrict__ w2,
                                                const float* __restrict__ b2,
                                                float* __restrict__ w2sum,
                                                float* __restrict__ b2sum,
                                                const float* __restrict__ x,
                                                const float* __restrict__ wg,
                                                float* __restrict__ g,
                                                u16* __restrict__ xbf,
                                                float* __restrict__ ssum) {
  __shared__ float tile[32][33];
  int b = blockIdx.x;
  int t = threadIdx.x;
  if (b < 4096) {
    // ---- w1 [E][M][H] fp32 -> w1t [E*H][M] bf16 ----
    int e   = b >> 11;
    int idx = b & 2047;
    int m0  = (idx >> 5) << 5;
    int h0  = (idx & 31) << 5;
    int r = t >> 3, q = t & 7;
    const float* src = w1 + ((size_t)e * MDIM + (m0 + r)) * HDIM + h0 + q * 4;
    f32x4 v = *(const f32x4*)src;
    tile[r][q*4+0] = v[0]; tile[r][q*4+1] = v[1];
    tile[r][q*4+2] = v[2]; tile[r][q*4+3] = v[3];
    __syncthreads();
    u16x4 o;
    o[0] = f2bf(tile[q*4+0][r]);
    o[1] = f2bf(tile[q*4+1][r]);
    o[2] = f2bf(tile[q*4+2][r]);
    o[3] = f2bf(tile[q*4+3][r]);
    u16* dst = w1t + ((size_t)e * HDIM + (h0 + r)) * MDIM + m0 + q * 4;
    *(u16x4*)dst = o;
  } else if (b < 4609) {
    // ---- w2sum / b2sum ----
    int bid  = b - 4096;
    int row  = bid * 4 + (t >> 6);
    int lane = t & 63;
    const float* src;
    if (row < NDIM)          src = w2 + (size_t)row * MDIM;
    else if (row < NDIM + 2) src = b2 + (size_t)(row - NDIM) * MDIM;
    else return;
    float acc = 0.f;
    for (int m = lane * 4; m < MDIM; m += 256) {
      f32x4 v = *(const f32x4*)(src + m);
      acc += v[0] + v[1] + v[2] + v[3];
    }
    #pragma unroll
    for (int off = 32; off; off >>= 1) acc += __shfl_xor(acc, off);
    if (lane == 0) {
      if (row < NDIM) w2sum[row] = acc;
      else            b2sum[row - NDIM] = acc;
    }
  } else if (b == 4609) {
    // ---- zero ssum ----
    f32x4 z = {0.f, 0.f, 0.f, 0.f};
    #pragma unroll
    for (int i = 0; i < 8; ++i)
      *(f32x4*)(ssum + (t + i * 256) * 4) = z;
  } else {
    // ---- fp32 gate + x->bf16 ----
    int bid  = b - 4610;
    int s    = bid * 4 + (t >> 6);
    int lane = t & 63;
    const float* xr = x + (size_t)s * MDIM;
    u16* xbr = xbf + (size_t)s * MDIM;
    float l0 = 0.f, l1 = 0.f;
    for (int m = lane * 4; m < MDIM; m += 256) {
      f32x4 xv = *(const f32x4*)(xr + m);
      f32x4 wa = *(const f32x4*)(wg + 2 * m);
      f32x4 wb = *(const f32x4*)(wg + 2 * m + 4);
      l0 += xv[0]*wa[0] + xv[1]*wa[2] + xv[2]*wb[0] + xv[3]*wb[2];
      l1 += xv[0]*wa[1] + xv[1]*wa[3] + xv[2]*wb[1] + xv[3]*wb[3];
      u16x4 o; o[0]=f2bf(xv[0]); o[1]=f2bf(xv[1]); o[2]=f2bf(xv[2]); o[3]=f2bf(xv[3]);
      *(u16x4*)(xbr + m) = o;
    }
    #pragma unroll
    for (int off = 32; off; off >>= 1) {
      l0 += __shfl_xor(l0, off);
      l1 += __shfl_xor(l1, off);
    }
    if (lane == 0) {
      float mx = fmaxf(l0, l1);
      float e0 = expf(l0 - mx), e1 = expf(l1 - mx);
      float inv = 1.f / (e0 + e1);
      g[2*s]   = e0 * inv;
      g[2*s+1] = e1 * inv;
    }
  }
}

// ---- main GEMM: 128x128 tile, 4 waves of 64x64, both operands gl2lds-staged ----
#define BM 128
#define BN 128
#define BK 64
#define KT (MDIM / BK)   // 32

#define MFMA_BF16 __builtin_amdgcn_mfma_f32_16x16x32_bf16

__global__ __launch_bounds__(256, 2) void gemm_fused(const u16* __restrict__ xbf,
                                                     const u16* __restrict__ w1t,
                                                     const float* __restrict__ b1,
                                                     const float* __restrict__ w2sum,
                                                     float* __restrict__ ssum) {
  __shared__ u16 As[2][BM * BK];   // 2 x 16 KB
  __shared__ u16 Bs[2][BN * BK];   // 2 x 16 KB  (total 64 KB -> 2 blocks/CU)

  int bid  = blockIdx.x;
  int tile = (bid & 7) * 64 + (bid >> 3);   // 512 % 8 == 0: bijective XCD swizzle
  int bn = tile & 15;
  int bm = tile >> 4;
  int gs0 = bm * BM;
  int gn0 = bn * BN;

  int tid  = threadIdx.x;
  int lane = tid & 63;
  int wid  = tid >> 6;               // 0..3
  int wr = wid >> 1, wc = wid & 1;   // 2(M) x 2(N); wave tile 64x64
  int fr = lane & 15, fg = lane >> 4;

  // staging: each wave stages 32 rows of A and 32 rows of B (4 issues of 8 each)
  int lr = lane >> 3;
  int lc = (lane & 7) ^ lr;          // inverse-swizzled source chunk (rule #21)
  int row0 = wid * 32;
  const u16* aS = xbf + (size_t)(gs0 + row0 + lr) * MDIM + lc * 8;
  const u16* bS = w1t + (size_t)(gn0 + row0 + lr) * MDIM + lc * 8;
  int sD = row0 * BK;                // wave-uniform LDS u16 offset (same for A,B)

  // frag-read offsets (u16 units), kk=0; kk=1 is ^32 (chunk ^ 4)
  int ch0 = (fg ^ (fr & 7)) * 8;
  int aOff[4], bOff[4];
  #pragma unroll
  for (int i = 0; i < 4; ++i) aOff[i] = (wr * 64 + i * 16 + fr) * BK + ch0;
  #pragma unroll
  for (int j = 0; j < 4; ++j) bOff[j] = (wc * 64 + j * 16 + fr) * BK + ch0;

  f32x4 acc[4][4] = {};

  // prologue: stage tile 0 into buffer 0 (8 issues per wave)
  #pragma unroll
  for (int q = 0; q < 4; ++q) {
    gl2lds16(aS + q * 8 * MDIM, &As[0][sD + q * 8 * BK]);
    gl2lds16(bS + q * 8 * MDIM, &Bs[0][sD + q * 8 * BK]);
  }

  for (int t = 0; t < KT; ++t) {
    const u16* Ac = &As[t & 1][0];
    const u16* Bc = &Bs[t & 1][0];
    u16* An = &As[(t & 1) ^ 1][0];
    u16* Bn = &Bs[(t & 1) ^ 1][0];
    bool notlast = (t + 1 < KT);

    // issue next tile's stage, then COUNTED wait: tile t's 8 loads landed,
    // tile t+1's 8 stay in flight across the barrier.
    if (notlast) {
      int nk = (t + 1) * BK;
      #pragma unroll
      for (int q = 0; q < 4; ++q) {
        gl2lds16(aS + nk + q * 8 * MDIM, An + sD + q * 8 * BK);
        gl2lds16(bS + nk + q * 8 * MDIM, Bn + sD + q * 8 * BK);
      }
      asm volatile("s_waitcnt vmcnt(8)" ::: "memory");
    } else {
      asm volatile("s_waitcnt vmcnt(0)" ::: "memory");
    }
    __builtin_amdgcn_s_barrier();   // tile t resident for all waves

    #pragma unroll
    for (int kk = 0; kk < 2; ++kk) {
      int x32 = kk * 32;
      s16x8 af[4], bf[4];
      #pragma unroll
      for (int i = 0; i < 4; ++i) af[i] = *(const s16x8*)(Ac + (aOff[i] ^ x32));
      #pragma unroll
      for (int j = 0; j < 4; ++j) bf[j] = *(const s16x8*)(Bc + (bOff[j] ^ x32));
      __builtin_amdgcn_s_setprio(1);
      #pragma unroll
      for (int i = 0; i < 4; ++i)
        #pragma unroll
        for (int j = 0; j < 4; ++j)
          acc[i][j] = MFMA_BF16(af[i], bf[j], acc[i][j], 0, 0, 0);
      __builtin_amdgcn_s_setprio(0);
    }

    __builtin_amdgcn_s_barrier();   // all reads of buf(t) done -> safe to overwrite
  }

  // epilogue: relu(acc + b1) * w2sum, reduce 64 cols -> atomicAdd ssum[e][s]
  int e = gn0 >> 10;   // BN=128 divides 1024: block within one expert
  float b1v[4], w2v[4];
  #pragma unroll
  for (int j = 0; j < 4; ++j) {
    int n = gn0 + wc * 64 + j * 16 + fr;
    b1v[j] = b1[n];
    w2v[j] = w2sum[n];
  }
  #pragma unroll
  for (int i = 0; i < 4; ++i) {
    #pragma unroll
    for (int r = 0; r < 4; ++r) {
      float sv = 0.f;
      #pragma unroll
      for (int j = 0; j < 4; ++j)
        sv += fmaxf(acc[i][j][r] + b1v[j], 0.f) * w2v[j];
      sv += __shfl_xor(sv, 1);
      sv += __shfl_xor(sv, 2);
      sv += __shfl_xor(sv, 4);
      sv += __shfl_xor(sv, 8);
      if (fr == 0) {
        int s = gs0 + wr * 64 + i * 16 + fg * 4 + r;
        atomicAdd(&ssum[(size_t)e * S_TOK + s], sv);
      }
    }
  }
}

// ---- summed = g0*(ssum0+b2sum0)+g1*(ssum1+b2sum1); log_softmax over T ----
__global__ __launch_bounds__(512) void finalize(const float* __restrict__ g,
                                                const float* __restrict__ ssum,
                                                const float* __restrict__ b2sum,
                                                float* __restrict__ out) {
  __shared__ float sA[8];
  __shared__ float sB[2];
  int b = blockIdx.x;
  int t = threadIdx.x;
  int s = b * TDIM + t;
  int lane = t & 63, wid = t >> 6;
  float g0 = g[2*s], g1 = g[2*s+1];
  float v = g0 * (ssum[s] + b2sum[0]) + g1 * (ssum[S_TOK + s] + b2sum[1]);
  float m = v;
  #pragma unroll
  for (int off = 32; off; off >>= 1) m = fmaxf(m, __shfl_xor(m, off));
  if (lane == 0) sA[wid] = m;
  __syncthreads();
  if (t == 0) {
    float mm = sA[0];
    #pragma unroll
    for (int i = 1; i < 8; ++i) mm = fmaxf(mm, sA[i]);
    sB[0] = mm;
  }
  __syncthreads();
  float gm = sB[0];
  float ex = expf(v - gm);
  float sum = ex;
  #pragma unroll
  for (int off = 32; off; off >>= 1) sum += __shfl_xor(sum, off);
  if (lane == 0) sA[wid] = sum;
  __syncthreads();
  if (t == 0) {
    float ss = 0.f;
    #pragma unroll
    for (int i = 0; i < 8; ++i) ss += sA[i];
    sB[1] = logf(ss);
  }
  __syncthreads();
  out[s] = v - gm - sB[1];
}

extern "C" void kernel_launch(void* const* d_in, const int* in_sizes, int n_in,
                              void* d_out, int out_size, void* d_ws, size_t ws_size,
                              hipStream_t stream) {
  const float* x  = (const float*)d_in[0];
  const float* wg = (const float*)d_in[1];
  const float* w1 = (const float*)d_in[2];
  const float* b1 = (const float*)d_in[3];
  const float* w2 = (const float*)d_in[4];
  const float* b2 = (const float*)d_in[5];
  float* out = (float*)d_out;

  char* ws = (char*)d_ws;
  u16*   w1t   = (u16*)ws;                     // 8,388,608 B
  u16*   xbf   = (u16*)(ws + 8388608);         // 16,777,216 B
  float* ssum  = (float*)(ws + 25165824);      // 32,768 B
  float* gbuf  = (float*)(ws + 25198592);      // 32,768 B
  float* w2sum = (float*)(ws + 25231360);      // 8,192 B
  float* b2sum = (float*)(ws + 25239552);      // 8 B

  hipLaunchKernelGGL(prep_all,   dim3(5634), dim3(256), 0, stream,
                     w1, w1t, w2, b2, w2sum, b2sum, x, wg, gbuf, xbf, ssum);
  hipLaunchKernelGGL(gemm_fused, dim3(512),  dim3(256), 0, stream, xbf, w1t, b1, w2sum, ssum);
  hipLaunchKernelGGL(finalize,   dim3(8),    dim3(512), 0, stream, gbuf, ssum, b2sum, out);
}